// Round 3
// baseline (666.308 us; speedup 1.0000x reference)
//
#include <hip/hip_runtime.h>
#include <hip/hip_bf16.h>
#include <hip/hip_fp16.h>
#include <math.h>

#define S_LEN   4096
#define B_SZ    32
#define D_DIM   64
#define L_LNK   13
#define NW_R    13
#define HF_W    128
#define HV_W    128
#define VOCAB_N 512
#define NC_N    2
#define SMASK   4095

__device__ __forceinline__ float gelu_erf(float x) {
    return 0.5f * x * (1.0f + erff(x * 0.70710678118654752440f));
}

__device__ __forceinline__ void fma4(float4& a, float s, float4 z) {
    a.x = fmaf(s, z.x, a.x); a.y = fmaf(s, z.y, a.y);
    a.z = fmaf(s, z.z, a.z); a.w = fmaf(s, z.w, a.w);
}

// bf16x4 pack/unpack (element order: lo16(x), hi16(x), lo16(y), hi16(y))
__device__ __forceinline__ uint2 pack4(float4 v) {
    __hip_bfloat162 a = __float22bfloat162_rn(float2{v.x, v.y});
    __hip_bfloat162 b = __float22bfloat162_rn(float2{v.z, v.w});
    uint2 r;
    r.x = *reinterpret_cast<unsigned int*>(&a);
    r.y = *reinterpret_cast<unsigned int*>(&b);
    return r;
}

__device__ __forceinline__ float4 unpack4(uint2 u) {
    float4 r;
    r.x = __uint_as_float(u.x << 16);
    r.y = __uint_as_float(u.x & 0xffff0000u);
    r.z = __uint_as_float(u.y << 16);
    r.w = __uint_as_float(u.y & 0xffff0000u);
    return r;
}

__device__ __forceinline__ void cvt2(unsigned int w, float& a, float& b) {
    __half2 h = *reinterpret_cast<__half2*>(&w);
    a = __half2float(h.x); b = __half2float(h.y);
}

// ---------------------------------------------------------------------------
// Kernel A: per-token tables. F_table now fp16 (rows padded to 16 halves).
// ---------------------------------------------------------------------------
__global__ __launch_bounds__(128)
void tables_kernel(const float* __restrict__ emb,
                   const float* __restrict__ fW1, const float* __restrict__ fb1,
                   const float* __restrict__ fW2, const float* __restrict__ fb2,
                   const float* __restrict__ vW1, const float* __restrict__ vb1,
                   const float* __restrict__ vW2, const float* __restrict__ vb2,
                   __half* __restrict__ F_table, float* __restrict__ V_table) {
    __shared__ float s_emb[D_DIM];
    __shared__ float s_H[HF_W];
    const int blk = blockIdx.x;
    const int tid = threadIdx.x;

    if (blk < NW_R * VOCAB_N) {
        const int k = blk >> 9;
        const int t = blk & (VOCAB_N - 1);
        if (tid < D_DIM) s_emb[tid] = emb[t * D_DIM + tid];
        __syncthreads();
        float acc = fb1[k * HF_W + tid];
        const float* w = fW1 + (size_t)k * D_DIM * HF_W + tid;
        #pragma unroll 8
        for (int d = 0; d < D_DIM; ++d) acc += s_emb[d] * w[d * HF_W];
        s_H[tid] = gelu_erf(acc);
        __syncthreads();
        if (tid < 16) {
            float o = 0.0f;
            if (tid < L_LNK) {
                o = fb2[k * L_LNK + tid];
                const float* w2 = fW2 + (size_t)k * HF_W * L_LNK + tid;
                #pragma unroll 8
                for (int h = 0; h < HF_W; ++h) o += s_H[h] * w2[h * L_LNK];
            }
            F_table[((size_t)(k * VOCAB_N + t)) * 16 + tid] = __float2half_rn(o);
        }
    } else {
        const int t = blk - NW_R * VOCAB_N;
        if (tid < D_DIM) s_emb[tid] = emb[t * D_DIM + tid];
        __syncthreads();
        float acc = vb1[tid];
        const float* w = vW1 + tid;
        #pragma unroll 8
        for (int d = 0; d < D_DIM; ++d) acc += s_emb[d] * w[d * HV_W];
        s_H[tid] = gelu_erf(acc);
        __syncthreads();
        if (tid < D_DIM) {
            float o = vb2[tid];
            const float* w2 = vW2 + tid;
            #pragma unroll 8
            for (int h = 0; h < HV_W; ++h) o += s_H[h] * w2[h * D_DIM];
            V_table[t * D_DIM + tid] = o;
        }
    }
}

// ---------------------------------------------------------------------------
// Kernel B: logits. 64 blocks x 1024 threads.
// ---------------------------------------------------------------------------
__global__ __launch_bounds__(1024)
void logits_kernel(const int* __restrict__ tok,
                   const float* __restrict__ V_table,
                   const float* __restrict__ finW,
                   const float* __restrict__ finb,
                   float* __restrict__ out) {
    const int b = blockIdx.x >> 1;
    const int c = blockIdx.x & 1;
    const int tid = threadIdx.x;
    const float4* fin4 = (const float4*)(finW + (size_t)c * S_LEN * D_DIM);
    const float4* V4 = (const float4*)V_table;
    float acc = 0.0f;
    #pragma unroll
    for (int it = 0; it < 4; ++it) {
        const int s = tid + it * 1024;
        const int t = tok[b * S_LEN + s];
        const float4* vp = V4 + t * 16;
        const float4* fp = fin4 + s * 16;
        #pragma unroll
        for (int j = 0; j < 16; ++j) {
            float4 v = vp[j], f = fp[j];
            acc += v.x * f.x + v.y * f.y + v.z * f.z + v.w * f.w;
        }
    }
    #pragma unroll
    for (int o = 32; o > 0; o >>= 1) acc += __shfl_down(acc, o, 64);
    __shared__ float s_part[16];
    if ((tid & 63) == 0) s_part[tid >> 6] = acc;
    __syncthreads();
    if (tid == 0) {
        float s = finb[c];
        #pragma unroll
        for (int i = 0; i < 16; ++i) s += s_part[i];
        out[b * NC_N + c] = s;
    }
}

// ---------------------------------------------------------------------------
// Kernel C: chord sparse-multiply.
// 512 threads/block, thread t owns rows t+512j (j=0..7).
//  - offsets 512/1024/2048 (+ own row 0) come from fp32 REGISTER arrays
//    (ping-pong zA/zB per round parity -> no repack, no dynamic indexing).
//  - remaining 9 offsets (1..256) read from single 32 KB bf16 LDS buffer.
//  - F coefficients fp16 (16 KB per-round working set -> L1-resident).
//  - V residual kept packed bf16 in regs (16 VGPRs).
// Register budget ~110 < 128 cap from __launch_bounds__(512,4): no spill.
// Grid: dim3(16, 32).
// ---------------------------------------------------------------------------
__global__ __launch_bounds__(512, 4)
void chord_kernel(const int* __restrict__ tok,
                  const __half* __restrict__ F_table,
                  const float* __restrict__ V_table,
                  float* __restrict__ Zout) {
    __shared__ uint2 Zs[S_LEN];   // 32 KB, bf16x4 per row-slice
    const int b = blockIdx.y;
    const int ds = blockIdx.x;
    const int t = threadIdx.x;
    const float4* V4 = (const float4*)V_table;

    int tokr[8];
    uint2 Vp[8];
    float4 zA[8], zB[8];
    #pragma unroll
    for (int j = 0; j < 8; ++j) {
        const int r = t + 512 * j;
        const int tk = tok[b * S_LEN + r];
        tokr[j] = tk;
        float4 v = V4[tk * 16 + ds];
        Vp[j] = pack4(v);
        zA[j] = v;
        Zs[r] = pack4(v);
    }
    __syncthreads();

    // One round: reads ZR (regs) + Zs (LDS), writes ZW (regs); then commits
    // ZW to Zs. WB==1 skips the LDS commit (last round).
#define ROUND(K, ZR, ZW, WB)                                                   \
    {                                                                          \
        _Pragma("unroll")                                                      \
        for (int j = 0; j < 8; ++j) {                                          \
            const int r = t + 512 * j;                                         \
            const __half* Fh =                                                 \
                F_table + ((size_t)((K) * VOCAB_N + tokr[j]) << 4);            \
            uint4 u0 = *(const uint4*)Fh;          /* halves 0..7  */          \
            uint2 u1 = *(const uint2*)(Fh + 8);    /* halves 8..11 */          \
            unsigned int u2 = *(const unsigned int*)(Fh + 12); /* half 12 */   \
            float f0, f1, f2, f3, f4, f5, f6, f7, f8, f9, f10, f11, f12, fpad; \
            cvt2(u0.x, f0, f1);  cvt2(u0.y, f2, f3);                           \
            cvt2(u0.z, f4, f5);  cvt2(u0.w, f6, f7);                           \
            cvt2(u1.x, f8, f9);  cvt2(u1.y, f10, f11);                         \
            cvt2(u2, f12, fpad); (void)fpad;                                   \
            float4 a = unpack4(Vp[j]);             /* residual */              \
            fma4(a, f0,  ZR[j]);                   /* off 0    */              \
            fma4(a, f10, ZR[(j + 1) & 7]);         /* off 512  */              \
            fma4(a, f11, ZR[(j + 2) & 7]);         /* off 1024 */              \
            fma4(a, f12, ZR[(j + 4) & 7]);         /* off 2048 */              \
            fma4(a, f1, unpack4(Zs[(r + 1)   & SMASK]));                       \
            fma4(a, f2, unpack4(Zs[(r + 2)   & SMASK]));                       \
            fma4(a, f3, unpack4(Zs[(r + 4)   & SMASK]));                       \
            fma4(a, f4, unpack4(Zs[(r + 8)   & SMASK]));                       \
            fma4(a, f5, unpack4(Zs[(r + 16)  & SMASK]));                       \
            fma4(a, f6, unpack4(Zs[(r + 32)  & SMASK]));                       \
            fma4(a, f7, unpack4(Zs[(r + 64)  & SMASK]));                       \
            fma4(a, f8, unpack4(Zs[(r + 128) & SMASK]));                       \
            fma4(a, f9, unpack4(Zs[(r + 256) & SMASK]));                       \
            ZW[j] = a;                                                         \
        }                                                                      \
        if (!(WB)) {                                                           \
            __syncthreads();                                                   \
            _Pragma("unroll")                                                  \
            for (int j = 0; j < 8; ++j) Zs[t + 512 * j] = pack4(ZW[j]);        \
            __syncthreads();                                                   \
        }                                                                      \
    }

    #pragma unroll 1
    for (int kk = 0; kk < (NW_R - 1) / 2; ++kk) {   // rounds 0..11
        ROUND(2 * kk,     zA, zB, 0)
        ROUND(2 * kk + 1, zB, zA, 0)
    }
    ROUND(NW_R - 1, zA, zB, 1)                       // round 12, no commit
#undef ROUND

    float4* Zo = (float4*)Zout;
    #pragma unroll
    for (int j = 0; j < 8; ++j) {
        const int r = t + 512 * j;
        Zo[((size_t)b * S_LEN + r) * 16 + ds] = zB[j];
    }
}

extern "C" void kernel_launch(void* const* d_in, const int* in_sizes, int n_in,
                              void* d_out, int out_size, void* d_ws, size_t ws_size,
                              hipStream_t stream) {
    const int*   tok  = (const int*)d_in[0];
    const float* emb  = (const float*)d_in[1];
    const float* fW1  = (const float*)d_in[2];
    const float* fb1  = (const float*)d_in[3];
    const float* fW2  = (const float*)d_in[4];
    const float* fb2  = (const float*)d_in[5];
    const float* vW1  = (const float*)d_in[6];
    const float* vb1  = (const float*)d_in[7];
    const float* vW2  = (const float*)d_in[8];
    const float* vb2  = (const float*)d_in[9];
    const float* finW = (const float*)d_in[10];
    const float* finb = (const float*)d_in[11];

    float* out = (float*)d_out;          // (B, NC) = 64 floats
    float* Z   = out + B_SZ * NC_N;      // (B, S, D) fp32

    float*  V_table = (float*)d_ws;                      // 512*64 f32 = 128 KB
    __half* F_table = (__half*)(V_table + VOCAB_N * D_DIM); // 13*512*16 f16

    tables_kernel<<<NW_R * VOCAB_N + VOCAB_N, 128, 0, stream>>>(
        emb, fW1, fb1, fW2, fb2, vW1, vb1, vW2, vb2, F_table, V_table);
    logits_kernel<<<B_SZ * NC_N, 1024, 0, stream>>>(tok, V_table, finW, finb, out);
    chord_kernel<<<dim3(16, B_SZ), 512, 0, stream>>>(tok, F_table, V_table, Z);
}

// Round 4
// 372.800 us; speedup vs baseline: 1.7873x; 1.7873x over previous
//
#include <hip/hip_runtime.h>
#include <hip/hip_bf16.h>
#include <hip/hip_fp16.h>
#include <math.h>

#define S_LEN   4096
#define B_SZ    32
#define D_DIM   64
#define L_LNK   13
#define NW_R    13
#define HF_W    128
#define HV_W    128
#define VOCAB_N 512
#define NC_N    2
#define SMASK   4095

typedef float vf4 __attribute__((ext_vector_type(4)));

__device__ __forceinline__ float gelu_erf(float x) {
    return 0.5f * x * (1.0f + erff(x * 0.70710678118654752440f));
}

// a += s * z, elementwise; ext-vector form so the backend can emit v_pk_fma_f32
__device__ __forceinline__ void fma4(vf4& a, float s, vf4 z) {
    vf4 sv = {s, s, s, s};
    a = __builtin_elementwise_fma(z, sv, a);
}

// bf16x4 pack/unpack (element order: lo16(x), hi16(x), lo16(y), hi16(y))
__device__ __forceinline__ uint2 pack4(vf4 v) {
    __hip_bfloat162 a = __float22bfloat162_rn(float2{v.x, v.y});
    __hip_bfloat162 b = __float22bfloat162_rn(float2{v.z, v.w});
    uint2 r;
    r.x = *reinterpret_cast<unsigned int*>(&a);
    r.y = *reinterpret_cast<unsigned int*>(&b);
    return r;
}

__device__ __forceinline__ vf4 unpack4(uint2 u) {
    vf4 r;
    r.x = __uint_as_float(u.x << 16);
    r.y = __uint_as_float(u.x & 0xffff0000u);
    r.z = __uint_as_float(u.y << 16);
    r.w = __uint_as_float(u.y & 0xffff0000u);
    return r;
}

__device__ __forceinline__ void cvt2(unsigned int w, float& a, float& b) {
    __half2 h = *reinterpret_cast<__half2*>(&w);
    a = __half2float(h.x); b = __half2float(h.y);
}

// ---------------------------------------------------------------------------
// Kernel A: per-token tables. 32 tokens per block so fW1[k] (32 KB) and
// fW2[k] become L1-resident across the token loop (R1-R3 re-read them from
// L2 once per token -> ~270 MB of L2 traffic; now ~1/32 of that).
// F_table fp16, rows padded to 16 halves (32 B). Grid: 13*16 F-blocks + 16
// V-blocks, 128 threads.
// ---------------------------------------------------------------------------
__global__ __launch_bounds__(128)
void tables_kernel(const float* __restrict__ emb,
                   const float* __restrict__ fW1, const float* __restrict__ fb1,
                   const float* __restrict__ fW2, const float* __restrict__ fb2,
                   const float* __restrict__ vW1, const float* __restrict__ vb1,
                   const float* __restrict__ vW2, const float* __restrict__ vb2,
                   __half* __restrict__ F_table, float* __restrict__ V_table) {
    __shared__ float s_emb[D_DIM];
    __shared__ float s_H[HF_W];
    const int blk = blockIdx.x;
    const int tid = threadIdx.x;

    if (blk < NW_R * 16) {
        const int k = blk >> 4;
        const int tg = blk & 15;
        for (int tt = 0; tt < 32; ++tt) {
            const int t = tg * 32 + tt;
            if (tid < D_DIM) s_emb[tid] = emb[t * D_DIM + tid];
            __syncthreads();
            float acc = fb1[k * HF_W + tid];
            const float* w = fW1 + (size_t)k * D_DIM * HF_W + tid;
            #pragma unroll 8
            for (int d = 0; d < D_DIM; ++d) acc += s_emb[d] * w[d * HF_W];
            s_H[tid] = gelu_erf(acc);
            __syncthreads();
            if (tid < 16) {
                float o = 0.0f;
                if (tid < L_LNK) {
                    o = fb2[k * L_LNK + tid];
                    const float* w2 = fW2 + (size_t)k * HF_W * L_LNK + tid;
                    #pragma unroll 8
                    for (int h = 0; h < HF_W; ++h) o += s_H[h] * w2[h * L_LNK];
                }
                F_table[((size_t)(k * VOCAB_N + t)) * 16 + tid] = __float2half_rn(o);
            }
            __syncthreads();   // s_emb/s_H reused next token
        }
    } else {
        const int tg = blk - NW_R * 16;
        for (int tt = 0; tt < 32; ++tt) {
            const int t = tg * 32 + tt;
            if (tid < D_DIM) s_emb[tid] = emb[t * D_DIM + tid];
            __syncthreads();
            float acc = vb1[tid];
            const float* w = vW1 + tid;
            #pragma unroll 8
            for (int d = 0; d < D_DIM; ++d) acc += s_emb[d] * w[d * HV_W];
            s_H[tid] = gelu_erf(acc);
            __syncthreads();
            if (tid < D_DIM) {
                float o = vb2[tid];
                const float* w2 = vW2 + tid;
                #pragma unroll 8
                for (int h = 0; h < HV_W; ++h) o += s_H[h] * w2[h * D_DIM];
                V_table[t * D_DIM + tid] = o;
            }
            __syncthreads();
        }
    }
}

// ---------------------------------------------------------------------------
// Kernel B: logits. 64 blocks x 1024 threads.
// ---------------------------------------------------------------------------
__global__ __launch_bounds__(1024)
void logits_kernel(const int* __restrict__ tok,
                   const float* __restrict__ V_table,
                   const float* __restrict__ finW,
                   const float* __restrict__ finb,
                   float* __restrict__ out) {
    const int b = blockIdx.x >> 1;
    const int c = blockIdx.x & 1;
    const int tid = threadIdx.x;
    const float4* fin4 = (const float4*)(finW + (size_t)c * S_LEN * D_DIM);
    const float4* V4 = (const float4*)V_table;
    float acc = 0.0f;
    #pragma unroll
    for (int it = 0; it < 4; ++it) {
        const int s = tid + it * 1024;
        const int t = tok[b * S_LEN + s];
        const float4* vp = V4 + t * 16;
        const float4* fp = fin4 + s * 16;
        #pragma unroll
        for (int j = 0; j < 16; ++j) {
            float4 v = vp[j], f = fp[j];
            acc += v.x * f.x + v.y * f.y + v.z * f.z + v.w * f.w;
        }
    }
    #pragma unroll
    for (int o = 32; o > 0; o >>= 1) acc += __shfl_down(acc, o, 64);
    __shared__ float s_part[16];
    if ((tid & 63) == 0) s_part[tid >> 6] = acc;
    __syncthreads();
    if (tid == 0) {
        float s = finb[c];
        #pragma unroll
        for (int i = 0; i < 16; ++i) s += s_part[i];
        out[b * NC_N + c] = s;
    }
}

// ---------------------------------------------------------------------------
// Kernel C: chord sparse-multiply. R1 skeleton (known no-spill), upgraded:
//  - Zs bf16 uint2, single 32 KB buffer, 2 barriers/round.
//  - zprev & V residual kept PACKED in regs (8+8 VGPRs, not 16+16):
//    offsets 0/1024/2048 come from zp[], 10 offsets from LDS.
//  - F coefficients fp16 from GLOBAL memory (16 KB/round/block -> L1-hot;
//    keeps the bottleneck DS pipe free, uses the idle VMEM pipe).
// Register budget: acc 16 + zp 8 + Vp 8 + tokf 4 + temps ~ 24 -> ~60 < 64.
// Grid: dim3(16, 32) x 1024 threads. DS floor ~46 us.
// ---------------------------------------------------------------------------
__global__ __launch_bounds__(1024)
void chord_kernel(const int* __restrict__ tok,
                  const __half* __restrict__ F_table,
                  const float* __restrict__ V_table,
                  float* __restrict__ Zout) {
    __shared__ uint2 Zs[S_LEN];   // 32 KB
    const int b = blockIdx.y;
    const int ds = blockIdx.x;
    const int t = threadIdx.x;
    const vf4* V4 = (const vf4*)V_table;

    unsigned tokf[4];   // byte offset of token's row within one k-slice
    uint2 Vp[4], zp[4];
    #pragma unroll
    for (int j = 0; j < 4; ++j) {
        const int r = t + 1024 * j;
        const int tk = tok[b * S_LEN + r];
        tokf[j] = (unsigned)tk * 32u;
        vf4 v = V4[tk * 16 + ds];
        uint2 p = pack4(v);
        Vp[j] = p; zp[j] = p;
        Zs[r] = p;
    }
    __syncthreads();

    vf4 acc[4];
    #pragma unroll 1
    for (int k = 0; k < NW_R; ++k) {
        const char* Fk = (const char*)F_table + (size_t)k * (VOCAB_N * 32);
        #pragma unroll
        for (int j = 0; j < 4; ++j) {
            const int r = t + 1024 * j;
            const char* Fr = Fk + tokf[j];
            uint4 u0 = *(const uint4*)Fr;                 // coeffs 0..7
            uint2 u1 = *(const uint2*)(Fr + 16);          // coeffs 8..11
            unsigned u2 = *(const unsigned*)(Fr + 24);    // coeff 12 (+pad)
            float c0, c1, c2, c3, c4, c5, c6, c7, c8, c9, c10, c11, c12, cp;
            cvt2(u0.x, c0, c1);  cvt2(u0.y, c2, c3);
            cvt2(u0.z, c4, c5);  cvt2(u0.w, c6, c7);
            cvt2(u1.x, c8, c9);  cvt2(u1.y, c10, c11);
            cvt2(u2, c12, cp);   (void)cp;

            vf4 a = unpack4(Vp[j]);                  // residual
            fma4(a, c0,  unpack4(zp[j]));            // offset 0
            fma4(a, c11, unpack4(zp[(j + 1) & 3]));  // offset 1024
            fma4(a, c12, unpack4(zp[(j + 2) & 3]));  // offset 2048
            fma4(a, c1,  unpack4(Zs[(r + 1)   & SMASK]));
            fma4(a, c2,  unpack4(Zs[(r + 2)   & SMASK]));
            fma4(a, c3,  unpack4(Zs[(r + 4)   & SMASK]));
            fma4(a, c4,  unpack4(Zs[(r + 8)   & SMASK]));
            fma4(a, c5,  unpack4(Zs[(r + 16)  & SMASK]));
            fma4(a, c6,  unpack4(Zs[(r + 32)  & SMASK]));
            fma4(a, c7,  unpack4(Zs[(r + 64)  & SMASK]));
            fma4(a, c8,  unpack4(Zs[(r + 128) & SMASK]));
            fma4(a, c9,  unpack4(Zs[(r + 256) & SMASK]));
            fma4(a, c10, unpack4(Zs[(r + 512) & SMASK]));
            acc[j] = a;
        }
        __syncthreads();
        if (k < NW_R - 1) {
            #pragma unroll
            for (int j = 0; j < 4; ++j) {
                uint2 p = pack4(acc[j]);
                zp[j] = p;
                Zs[t + 1024 * j] = p;
            }
            __syncthreads();
        }
    }

    #pragma unroll
    for (int j = 0; j < 4; ++j) {
        const int r = t + 1024 * j;
        *(vf4*)(Zout + (((size_t)b * S_LEN + r) << 6) + ds * 4) = acc[j];
    }
}

extern "C" void kernel_launch(void* const* d_in, const int* in_sizes, int n_in,
                              void* d_out, int out_size, void* d_ws, size_t ws_size,
                              hipStream_t stream) {
    const int*   tok  = (const int*)d_in[0];
    const float* emb  = (const float*)d_in[1];
    const float* fW1  = (const float*)d_in[2];
    const float* fb1  = (const float*)d_in[3];
    const float* fW2  = (const float*)d_in[4];
    const float* fb2  = (const float*)d_in[5];
    const float* vW1  = (const float*)d_in[6];
    const float* vb1  = (const float*)d_in[7];
    const float* vW2  = (const float*)d_in[8];
    const float* vb2  = (const float*)d_in[9];
    const float* finW = (const float*)d_in[10];
    const float* finb = (const float*)d_in[11];

    float* out = (float*)d_out;          // (B, NC) = 64 floats
    float* Z   = out + B_SZ * NC_N;      // (B, S, D) fp32

    float*  V_table = (float*)d_ws;                         // 512*64 f32
    __half* F_table = (__half*)(V_table + VOCAB_N * D_DIM); // 13*512*16 f16

    tables_kernel<<<NW_R * 16 + 16, 128, 0, stream>>>(
        emb, fW1, fb1, fW2, fb2, vW1, vb1, vW2, vb2, F_table, V_table);
    logits_kernel<<<B_SZ * NC_N, 1024, 0, stream>>>(tok, V_table, finW, finb, out);
    chord_kernel<<<dim3(16, B_SZ), 1024, 0, stream>>>(tok, F_table, V_table, Z);
}

// Round 5
// 232.812 us; speedup vs baseline: 2.8620x; 1.6013x over previous
//
#include <hip/hip_runtime.h>
#include <hip/hip_bf16.h>
#include <hip/hip_fp16.h>
#include <math.h>

#define S_LEN   4096
#define B_SZ    32
#define D_DIM   64
#define L_LNK   13
#define NW_R    13
#define HF_W    128
#define HV_W    128
#define VOCAB_N 512
#define NC_N    2

#define STRIDE  512            // chord rows per thread-stride
#define NROW    8              // rows per thread
#define MIRROR  256            // mirrored rows (max LDS link offset)
#define BUFN    (S_LEN + MIRROR)

typedef float vf4 __attribute__((ext_vector_type(4)));

__device__ __forceinline__ float gelu_erf(float x) {
    return 0.5f * x * (1.0f + erff(x * 0.70710678118654752440f));
}

__device__ __forceinline__ void fma4(vf4& a, float s, vf4 z) {
    vf4 sv = {s, s, s, s};
    a = __builtin_elementwise_fma(z, sv, a);
}

// bf16x4 pack/unpack (order: lo16(x), hi16(x), lo16(y), hi16(y))
__device__ __forceinline__ uint2 pack4(vf4 v) {
    __hip_bfloat162 a = __float22bfloat162_rn(float2{v.x, v.y});
    __hip_bfloat162 b = __float22bfloat162_rn(float2{v.z, v.w});
    uint2 r;
    r.x = *reinterpret_cast<unsigned int*>(&a);
    r.y = *reinterpret_cast<unsigned int*>(&b);
    return r;
}

__device__ __forceinline__ vf4 unpack4(uint2 u) {
    vf4 r;
    r.x = __uint_as_float(u.x << 16);
    r.y = __uint_as_float(u.x & 0xffff0000u);
    r.z = __uint_as_float(u.y << 16);
    r.w = __uint_as_float(u.y & 0xffff0000u);
    return r;
}

__device__ __forceinline__ void cvt2(unsigned int w, float& a, float& b) {
    __half2 h = *reinterpret_cast<__half2*>(&w);
    a = __half2float(h.x); b = __half2float(h.y);
}

// ---------------------------------------------------------------------------
// Kernel A: per-token tables (R1 structure — max parallelism; the R4
// 32-token-serial variant cost ~100 us of idle chip). F_table fp16,
// rows padded to 16 halves (32 B). Grid: 13*512 + 512 blocks x 128 thr.
// ---------------------------------------------------------------------------
__global__ __launch_bounds__(128)
void tables_kernel(const float* __restrict__ emb,
                   const float* __restrict__ fW1, const float* __restrict__ fb1,
                   const float* __restrict__ fW2, const float* __restrict__ fb2,
                   const float* __restrict__ vW1, const float* __restrict__ vb1,
                   const float* __restrict__ vW2, const float* __restrict__ vb2,
                   __half* __restrict__ F_table, float* __restrict__ V_table) {
    __shared__ float s_emb[D_DIM];
    __shared__ float s_H[HF_W];
    const int blk = blockIdx.x;
    const int tid = threadIdx.x;

    if (blk < NW_R * VOCAB_N) {
        const int k = blk >> 9;
        const int t = blk & (VOCAB_N - 1);
        if (tid < D_DIM) s_emb[tid] = emb[t * D_DIM + tid];
        __syncthreads();
        float acc = fb1[k * HF_W + tid];
        const float* w = fW1 + (size_t)k * D_DIM * HF_W + tid;
        #pragma unroll 8
        for (int d = 0; d < D_DIM; ++d) acc += s_emb[d] * w[d * HF_W];
        s_H[tid] = gelu_erf(acc);
        __syncthreads();
        if (tid < 16) {
            float o = 0.0f;
            if (tid < L_LNK) {
                o = fb2[k * L_LNK + tid];
                const float* w2 = fW2 + (size_t)k * HF_W * L_LNK + tid;
                #pragma unroll 8
                for (int h = 0; h < HF_W; ++h) o += s_H[h] * w2[h * L_LNK];
            }
            F_table[((size_t)(k * VOCAB_N + t)) * 16 + tid] = __float2half_rn(o);
        }
    } else {
        const int t = blk - NW_R * VOCAB_N;
        if (tid < D_DIM) s_emb[tid] = emb[t * D_DIM + tid];
        __syncthreads();
        float acc = vb1[tid];
        const float* w = vW1 + tid;
        #pragma unroll 8
        for (int d = 0; d < D_DIM; ++d) acc += s_emb[d] * w[d * HV_W];
        s_H[tid] = gelu_erf(acc);
        __syncthreads();
        if (tid < D_DIM) {
            float o = vb2[tid];
            const float* w2 = vW2 + tid;
            #pragma unroll 8
            for (int h = 0; h < HV_W; ++h) o += s_H[h] * w2[h * D_DIM];
            V_table[t * D_DIM + tid] = o;
        }
    }
}

// ---------------------------------------------------------------------------
// Kernel B: logits, 256 blocks x 512 thr (1 block/CU). Block (b, chunk of
// 512 rows): each thread does one row, both classes (V row reused), then
// block-reduce + atomicAdd. out[0:64] must be zeroed beforehand (memset).
// ---------------------------------------------------------------------------
__global__ __launch_bounds__(512)
void logits_kernel(const int* __restrict__ tok,
                   const float* __restrict__ V_table,
                   const float* __restrict__ finW,
                   const float* __restrict__ finb,
                   float* __restrict__ out) {
    const int b = blockIdx.x >> 3;
    const int chunk = blockIdx.x & 7;
    const int tid = threadIdx.x;
    const int s = chunk * 512 + tid;
    const int t = tok[b * S_LEN + s];
    const float4* vp = (const float4*)V_table + t * 16;
    const float4* f0 = (const float4*)finW + s * 16;
    const float4* f1 = (const float4*)(finW + (size_t)S_LEN * D_DIM) + s * 16;
    float a0 = 0.0f, a1 = 0.0f;
    #pragma unroll
    for (int j = 0; j < 16; ++j) {
        float4 v = vp[j], x = f0[j], y = f1[j];
        a0 += v.x * x.x + v.y * x.y + v.z * x.z + v.w * x.w;
        a1 += v.x * y.x + v.y * y.y + v.z * y.z + v.w * y.w;
    }
    #pragma unroll
    for (int o = 32; o > 0; o >>= 1) {
        a0 += __shfl_down(a0, o, 64);
        a1 += __shfl_down(a1, o, 64);
    }
    __shared__ float sp[2][8];
    if ((tid & 63) == 0) { sp[0][tid >> 6] = a0; sp[1][tid >> 6] = a1; }
    __syncthreads();
    if (tid == 0) {
        float s0 = 0.0f, s1 = 0.0f;
        #pragma unroll
        for (int i = 0; i < 8; ++i) { s0 += sp[0][i]; s1 += sp[1][i]; }
        if (chunk == 0) { s0 += finb[0]; s1 += finb[1]; }
        atomicAdd(&out[b * NC_N + 0], s0);
        atomicAdd(&out[b * NC_N + 1], s1);
    }
}

// ---------------------------------------------------------------------------
// Kernel C: chord sparse-multiply.
// 512 threads, thread t owns rows t+512j (j=0..7):
//  - offsets 0/512/1024/2048 from packed-bf16 register array zp[8].
//  - 9 LDS links (1..256) from mirrored DOUBLE-buffered bf16 Zs
//    (rows [0,256) duplicated at [4096,4352)) -> ds_read_b64 with immediate
//    offsets, ONE barrier per round.
//  - F fp16 rows loaded with SGPR base (F_table + k*16KB) + voffset tokf[j].
// LDS 2*4352*8 = 69,632 B -> 2 blocks/CU -> 16 waves/CU -> 128-VGPR budget
// (__launch_bounds__(512,4)); live state ~110 VGPR, no spill expected.
// Grid: dim3(16, 32).
// ---------------------------------------------------------------------------
__global__ __launch_bounds__(512, 4)
void chord_kernel(const int* __restrict__ tok,
                  const __half* __restrict__ F_table,
                  const float* __restrict__ V_table,
                  float* __restrict__ Zout) {
    __shared__ uint2 Zs[2][BUFN];
    const int b = blockIdx.y;
    const int ds = blockIdx.x;
    const int t = threadIdx.x;
    const vf4* V4 = (const vf4*)V_table;

    unsigned tokf[NROW];
    uint2 Vp[NROW], zp[NROW];
    #pragma unroll
    for (int j = 0; j < NROW; ++j) {
        const int r = t + STRIDE * j;
        const int tk = tok[b * S_LEN + r];
        tokf[j] = (unsigned)tk * 32u;
        vf4 v = V4[tk * 16 + ds];
        uint2 p = pack4(v);
        Vp[j] = p; zp[j] = p;
        Zs[0][r] = p;
    }
    if (t < MIRROR) Zs[0][S_LEN + t] = zp[0];   // waves 0..3: uniform branch
    __syncthreads();

    int cur = 0;
    vf4 acc[NROW];
    #pragma unroll 1
    for (int k = 0; k < NW_R; ++k) {
        const char* Fk = (const char*)F_table + (size_t)k * (VOCAB_N * 32);
        const uint2* Zc = Zs[cur];
        #pragma unroll
        for (int j = 0; j < NROW; ++j) {
            const int r = t + STRIDE * j;
            const char* Fr = Fk + tokf[j];
            uint4 u0 = *(const uint4*)Fr;                 // coeffs 0..7
            uint2 u1 = *(const uint2*)(Fr + 16);          // coeffs 8..11
            unsigned u2 = *(const unsigned*)(Fr + 24);    // coeff 12 (+pad)
            // coeff index -> offset: c0:0 c1:1 c2:2 c3:4 c4:8 c5:16 c6:32
            //                        c7:64 c8:128 c9:256 c10:512 c11:1024 c12:2048
            float c0,c1,c2,c3,c4,c5,c6,c7,c8,c9,c10,c11,c12,cp;
            cvt2(u0.x,c0,c1);  cvt2(u0.y,c2,c3);
            cvt2(u0.z,c4,c5);  cvt2(u0.w,c6,c7);
            cvt2(u1.x,c8,c9);  cvt2(u1.y,c10,c11);
            cvt2(u2,c12,cp);   (void)cp;

            vf4 a = unpack4(Vp[j]);                    // residual
            fma4(a, c0,  unpack4(zp[j]));              // off 0
            fma4(a, c10, unpack4(zp[(j + 1) & 7]));    // off 512
            fma4(a, c11, unpack4(zp[(j + 2) & 7]));    // off 1024
            fma4(a, c12, unpack4(zp[(j + 4) & 7]));    // off 2048
            fma4(a, c1, unpack4(Zc[r + 1]));
            fma4(a, c2, unpack4(Zc[r + 2]));
            fma4(a, c3, unpack4(Zc[r + 4]));
            fma4(a, c4, unpack4(Zc[r + 8]));
            fma4(a, c5, unpack4(Zc[r + 16]));
            fma4(a, c6, unpack4(Zc[r + 32]));
            fma4(a, c7, unpack4(Zc[r + 64]));
            fma4(a, c8, unpack4(Zc[r + 128]));
            fma4(a, c9, unpack4(Zc[r + 256]));
            acc[j] = a;
        }
        if (k < NW_R - 1) {
            uint2* Zn = Zs[cur ^ 1];
            #pragma unroll
            for (int j = 0; j < NROW; ++j) {
                uint2 p = pack4(acc[j]);
                zp[j] = p;
                Zn[t + STRIDE * j] = p;
            }
            if (t < MIRROR) Zn[S_LEN + t] = zp[0];
        }
        __syncthreads();   // single barrier/round (double buffer -> no WAR)
        cur ^= 1;
    }

    #pragma unroll
    for (int j = 0; j < NROW; ++j) {
        const int r = t + STRIDE * j;
        *(vf4*)(Zout + (((size_t)b * S_LEN + r) << 6) + ds * 4) = acc[j];
    }
}

extern "C" void kernel_launch(void* const* d_in, const int* in_sizes, int n_in,
                              void* d_out, int out_size, void* d_ws, size_t ws_size,
                              hipStream_t stream) {
    const int*   tok  = (const int*)d_in[0];
    const float* emb  = (const float*)d_in[1];
    const float* fW1  = (const float*)d_in[2];
    const float* fb1  = (const float*)d_in[3];
    const float* fW2  = (const float*)d_in[4];
    const float* fb2  = (const float*)d_in[5];
    const float* vW1  = (const float*)d_in[6];
    const float* vb1  = (const float*)d_in[7];
    const float* vW2  = (const float*)d_in[8];
    const float* vb2  = (const float*)d_in[9];
    const float* finW = (const float*)d_in[10];
    const float* finb = (const float*)d_in[11];

    float* out = (float*)d_out;          // (B, NC) = 64 floats
    float* Z   = out + B_SZ * NC_N;      // (B, S, D) fp32

    float*  V_table = (float*)d_ws;                         // 512*64 f32
    __half* F_table = (__half*)(V_table + VOCAB_N * D_DIM); // 13*512*16 f16

    hipMemsetAsync(out, 0, B_SZ * NC_N * sizeof(float), stream);
    tables_kernel<<<NW_R * VOCAB_N + VOCAB_N, 128, 0, stream>>>(
        emb, fW1, fb1, fW2, fb2, vW1, vb1, vW2, vb2, F_table, V_table);
    logits_kernel<<<B_SZ * NC_N * 4, 512, 0, stream>>>(tok, V_table, finW, finb, out);
    chord_kernel<<<dim3(16, B_SZ), 512, 0, stream>>>(tok, F_table, V_table, Z);
}